// Round 9
// baseline (118.394 us; speedup 1.0000x reference)
//
#include <hip/hip_runtime.h>

typedef unsigned short u16;
typedef unsigned int u32;
typedef unsigned long long u64;
typedef __attribute__((ext_vector_type(8))) short short8;
typedef __attribute__((ext_vector_type(4))) float f32x4;
typedef __attribute__((ext_vector_type(4))) u32 u32x4;

#define BATCH 8
#define NSEQ 1024
#define DMODEL 512
#define HDIM 64
// QK_SCALE * log2(e): softmax computed in exp2 domain
#define SCALE_LOG2E 0.06375871114929199f
#define FIXED_MAX 16.0f

// workspace byte offsets
#define O_QBF 0ULL
#define O_KBF 8388608ULL
#define O_WB  16777216ULL
#define O_QP  19922944ULL
#define O_KP  28311552ULL
#define O_VP  36700160ULL

__device__ __forceinline__ u16 f2bf(float f) {
  u32 u = __float_as_uint(f);
  u = (u + 0x7fffu + ((u >> 16) & 1u)) >> 16;
  return (u16)u;
}
__device__ __forceinline__ float bf2f(u16 s) {
  return __uint_as_float(((u32)s) << 16);
}
__device__ __forceinline__ void gload16(const void* g, void* l) {
  __builtin_amdgcn_global_load_lds((const __attribute__((address_space(1))) void*)g,
                                   (__attribute__((address_space(3))) void*)l, 16, 0, 0);
}
// pack two f32 -> u32 of 2 bf16 (lo = a, hi = b)
__device__ __forceinline__ u32 cvtpk(float a, float b) {
  u32 r;
  asm("v_cvt_pk_bf16_f32 %0, %1, %2" : "=v"(r) : "v"(a), "v"(b));
  return r;
}

// ---------------------------------------------------------------------------
// prep: fp32->bf16 Q/K, transpose-convert weights to [N][K],
//       M -> bf16 additive bias {0, -32768} stored in d_out (dead until ln1)
// ---------------------------------------------------------------------------
__global__ __launch_bounds__(256) void prep_kernel(
    const float* __restrict__ Q, const float* __restrict__ K,
    const float* __restrict__ Wq, const float* __restrict__ Wk,
    const float* __restrict__ Wv, const float* __restrict__ Wo,
    const int* __restrict__ M,
    u16* __restrict__ Qbf, u16* __restrict__ Kbf, u16* __restrict__ Wb,
    u16* __restrict__ Mbias)
{
  __shared__ float lds[64 * 68];
  const int bi = blockIdx.x, t = threadIdx.x;
  if (bi < 4096) {
    const float* src = (bi < 2048) ? Q : K;
    u16* dst = (bi < 2048) ? Qbf : Kbf;
    const int lb = bi & 2047;
    const size_t base = ((size_t)lb * 256 + t) * 8;
    float4 a = *(const float4*)(src + base);
    float4 c = *(const float4*)(src + base + 4);
    short8 o;
    o[0] = (short)f2bf(a.x); o[1] = (short)f2bf(a.y);
    o[2] = (short)f2bf(a.z); o[3] = (short)f2bf(a.w);
    o[4] = (short)f2bf(c.x); o[5] = (short)f2bf(c.y);
    o[6] = (short)f2bf(c.z); o[7] = (short)f2bf(c.w);
    *(short8*)(dst + base) = o;
  } else if (bi < 4352) {
    const int qid = bi - 4096;
    const int w = qid >> 6;
    const int tt = qid & 63;
    const int tr = tt >> 3, tc = tt & 7;          // 64x64 tile at (tr*64 k, tc*64 n)
    const float* W = (w == 0) ? Wq : (w == 1) ? Wk : (w == 2) ? Wv : Wo;
#pragma unroll
    for (int j = 0; j < 4; ++j) {
      int vi = j * 256 + t;
      int row = vi >> 4, c4 = vi & 15;
      float4 v = *(const float4*)(W + (size_t)(tr * 64 + row) * 512 + tc * 64 + c4 * 4);
      lds[row * 68 + c4 * 4 + 0] = v.x;
      lds[row * 68 + c4 * 4 + 1] = v.y;
      lds[row * 68 + c4 * 4 + 2] = v.z;
      lds[row * 68 + c4 * 4 + 3] = v.w;
    }
    __syncthreads();
    // 64 n-rows x 8 k8-chunks = 512 short8 stores -> exactly 2 iterations
#pragma unroll
    for (int j = 0; j < 2; ++j) {
      int oi = j * 256 + t;
      int nl = oi >> 3, k8 = oi & 7;
      short8 o;
#pragma unroll
      for (int i = 0; i < 8; ++i) o[i] = (short)f2bf(lds[(k8 * 8 + i) * 68 + nl]);
      *(short8*)(Wb + (size_t)w * 262144 + (size_t)(tc * 64 + nl) * 512 + tr * 64 + k8 * 8) = o;
    }
  } else {
    // mask -> bf16 additive bias: keep -> 0.0, masked -> -32768.0 (0xC700)
    const int pb = bi - 4352;                     // 2048 blocks
    const size_t idx = ((size_t)pb * 256 + t) * 16;
    const int4* Ms = (const int4*)(M + idx);
    int4 m0 = Ms[0], m1 = Ms[1], m2 = Ms[2], m3 = Ms[3];
    int mv[16] = {m0.x, m0.y, m0.z, m0.w, m1.x, m1.y, m1.z, m1.w,
                  m2.x, m2.y, m2.z, m2.w, m3.x, m3.y, m3.z, m3.w};
    short8 o0, o1;
#pragma unroll
    for (int i = 0; i < 8; ++i) {
      o0[i] = mv[i] ? (short)0 : (short)0xC700;
      o1[i] = mv[8 + i] ? (short)0 : (short)0xC700;
    }
    *(short8*)(Mbias + idx) = o0;
    *(short8*)(Mbias + idx + 8) = o1;
  }
}

// ---------------------------------------------------------------------------
// gemm_bt: C[M=8192,N=512] = A[M,512] * Wb^T (Wb stored [N][K]) + bias
// ---------------------------------------------------------------------------
template<int MODE>
__global__ __launch_bounds__(256) void gemm_bt(
    const u16* __restrict__ Aq, const u16* __restrict__ Ak,
    const u16* __restrict__ Wb,
    const float* __restrict__ b0, const float* __restrict__ b1, const float* __restrict__ b2,
    u16* __restrict__ outp, const u16* __restrict__ resid)
{
  __shared__ __align__(16) char Alds[8192];
  __shared__ __align__(16) char Blds[8192];
  const int tid = threadIdx.x;
  const int wv = tid >> 6, lane = tid & 63;
  const int g16 = lane >> 4, l16 = lane & 15;
  const int wr = wv >> 1, wc = wv & 1;
  const int bx = blockIdx.x, by = blockIdx.y, bz = blockIdx.z;

  const u16* A; const u16* W; const float* bias; u16* out;
  if (MODE == 0) {
    A = (bz == 0) ? Aq : Ak;
    W = Wb + (size_t)bz * 262144;
    bias = (bz == 0) ? b0 : ((bz == 1) ? b1 : b2);
    out = outp + (size_t)bz * 4194304;
  } else {
    A = Aq; W = Wb; bias = b0; out = outp;
  }

  const int m0 = bx * 128, n0 = by * 128;
  f32x4 acc[4][4] = {};

  for (int kt = 0; kt < 16; ++kt) {
    const int k0 = kt * 32;
#pragma unroll
    for (int r = 0; r < 2; ++r) {
      int idx = r * 256 + tid;
      int row = idx >> 2, sl = idx & 3;
      gload16(A + (size_t)(m0 + row) * 512 + k0 + sl * 8, Alds + r * 4096 + wv * 1024);
      gload16(W + (size_t)(n0 + row) * 512 + k0 + sl * 8, Blds + r * 4096 + wv * 1024);
    }
    __syncthreads();
    short8 af[4], bfr[4];
#pragma unroll
    for (int mt = 0; mt < 4; ++mt)
      af[mt] = *(const short8*)(Alds + (wr * 64 + mt * 16 + l16) * 64 + g16 * 16);
#pragma unroll
    for (int nt = 0; nt < 4; ++nt)
      bfr[nt] = *(const short8*)(Blds + (wc * 64 + nt * 16 + l16) * 64 + g16 * 16);
#pragma unroll
    for (int mt = 0; mt < 4; ++mt)
#pragma unroll
      for (int nt = 0; nt < 4; ++nt)
        acc[mt][nt] = __builtin_amdgcn_mfma_f32_16x16x32_bf16(af[mt], bfr[nt], acc[mt][nt], 0, 0, 0);
    __syncthreads();
  }

#pragma unroll
  for (int nt = 0; nt < 4; ++nt) {
    int col = n0 + wc * 64 + nt * 16 + l16;
    float bcol = bias[col];
#pragma unroll
    for (int mt = 0; mt < 4; ++mt) {
#pragma unroll
      for (int r = 0; r < 4; ++r) {
        int row = m0 + wr * 64 + mt * 16 + g16 * 4 + r;
        float v = acc[mt][nt][r] + bcol;
        if (MODE == 1) {
          v = fmaxf(v, 0.f) + bf2f(resid[(size_t)row * 512 + col]);
        }
        out[(size_t)row * 512 + col] = f2bf(v);
      }
    }
  }
}

// ---------------------------------------------------------------------------
// flash attention, swapped-operand, static-max softmax, LANE-LOCAL PV.
// Key identity: MFMA contracts over k, so the k-LABELING of PV is arbitrary.
// Pick kappa(g16,j,kc) = kc*32 + (j>>2)*16 + g16*4 + (j&3) — exactly the
// k-distribution QK^T's C/D output already has. Then the PV B-fragment is the
// lane's own cvt_pk-packed registers (NO P_lds, no shuffles), and the
// permutation is absorbed into WHICH global rows V-staging loads (same
// coalescing). LDS drops 40->32 KB => 4 blocks/CU.
// Per tile: s_waitcnt vmcnt(12) lgkmcnt(0) + raw s_barrier (never vmcnt(0)).
// ---------------------------------------------------------------------------
__global__ __launch_bounds__(256, 4) void attn_kernel(
    const u16* __restrict__ Qp, const u16* __restrict__ Kp, const u16* __restrict__ Vp,
    const u16* __restrict__ Mbias, u16* __restrict__ O1)
{
  __shared__ __align__(16) char K_lds[2][8192];    // [64 k][64 dk] bf16, chunk-swizzled
  __shared__ __align__(16) char VT_lds[2][8192];   // [64 dv][64 kappa] bf16, chunk-swizzled

  const int tid = threadIdx.x;
  const int wv = tid >> 6, lane = tid & 63;
  const int g16 = lane >> 4, l16 = lane & 15;
  const int l7 = l16 & 7;

  // bijective XCD swizzle: all 16 q-tiles of a (b,h) share one XCD's L2
  const int wg = blockIdx.x;                       // 1024 blocks
  const int swz = (wg & 7) * 128 + (wg >> 3);
  const int qt = swz & 15;
  const int h = (swz >> 4) & 7;
  const int b = swz >> 7;
  const int qg = qt * 64;
  const int hb = h * HDIM;
  const size_t batch_row = (size_t)b * NSEQ;

  const int q = qg + wv * 16 + l16;                // this lane's q column
  const int dv2 = (tid & 31) * 2;                  // V staging lanes
  const int kg = tid >> 5;                         // 0..7 = kc*4+gg
  const int v_kc = kg >> 2, v_gg = kg & 3;

  // hoist Q as B-operand frags, pre-scaled into the exp2 domain
  short8 b_q[2];
#pragma unroll
  for (int c = 0; c < 2; ++c) {
    short8 raw = *(const short8*)(Qp + (batch_row + q) * DMODEL + hb + c * 32 + g16 * 8);
    short8 sc;
#pragma unroll
    for (int j = 0; j < 8; ++j) sc[j] = (short)f2bf(bf2f((u16)raw[j]) * SCALE_LOG2E);
    b_q[c] = sc;
  }

  const u64* Mq = (const u64*)(Mbias + (batch_row + q) * 1024);

  auto stageK = [&](int kt2, char* dst) {
#pragma unroll
    for (int r = 0; r < 2; ++r) {
      int idx = r * 256 + tid;
      int row = idx >> 3, sl = idx & 7;
      int chunk = sl ^ (row & 7);
      gload16(Kp + (batch_row + kt2 * 64 + row) * DMODEL + hb + chunk * 8,
              dst + r * 4096 + wv * 1024);
    }
  };
  // load V rows in kappa order: thread (kg=kc*4+gg, dv2) grabs
  // rows kc*32 + (j>>2)*16 + gg*4 + (j&3) so its 8 values form ONE LDS chunk
  // that the PV A-frag reads as kappa-slots (g16=gg, kc).
  auto loadV = [&](int kt2, u32 (&vr)[8]) {
#pragma unroll
    for (int j = 0; j < 8; ++j) {
      int row = v_kc * 32 + (j >> 2) * 16 + v_gg * 4 + (j & 3);
      vr[j] = *(const u32*)(Vp + (batch_row + kt2 * 64 + row) * DMODEL + hb + dv2);
    }
  };
  auto writeVT = [&](const u32 (&vr)[8], char* dstv) {
    u32x4 lo, hi;
#pragma unroll
    for (int i = 0; i < 4; ++i) {
      lo[i] = __builtin_amdgcn_perm(vr[2 * i + 1], vr[2 * i], 0x05040100u);
      hi[i] = __builtin_amdgcn_perm(vr[2 * i + 1], vr[2 * i], 0x07060302u);
    }
    *(u32x4*)(dstv + dv2 * 128 + ((kg ^ (dv2 & 7)) << 4)) = lo;
    *(u32x4*)(dstv + (dv2 + 1) * 128 + ((kg ^ ((dv2 + 1) & 7)) << 4)) = hi;
  };

  float lL = 0.f;
  f32x4 accO[4] = {};

  u32 vreg[8];
  u64 biasA[4], biasB[4];

  // prologue: stage tile 0; entering tile 0 the queue is bias0[4], V1[8]
  stageK(0, &K_lds[0][0]);
  loadV(0, vreg);
#pragma unroll
  for (int kf = 0; kf < 4; ++kf) biasA[kf] = Mq[kf * 4 + g16];
  writeVT(vreg, &VT_lds[0][0]);   // compiler-counted wait retires K0+V0 here
  loadV(1, vreg);

#define ATTN_TILE(KT, CUR, BIN, BOUT)                                          \
  do {                                                                         \
    asm volatile("s_waitcnt vmcnt(12) lgkmcnt(0)" ::: "memory");               \
    __builtin_amdgcn_sched_barrier(0);                                         \
    __builtin_amdgcn_s_barrier();                                              \
    __builtin_amdgcn_sched_barrier(0);                                         \
    char* Kc = &K_lds[CUR][0];                                                 \
    char* Vc = &VT_lds[CUR][0];                                                \
    if ((KT) < 15) {                                                           \
      writeVT(vreg, &VT_lds[(CUR) ^ 1][0]);                                    \
      stageK((KT) + 1, &K_lds[(CUR) ^ 1][0]);                                  \
      loadV((KT) + 2 < 16 ? (KT) + 2 : 15, vreg);                              \
      _Pragma("unroll")                                                        \
      for (int kf = 0; kf < 4; ++kf)                                           \
        BOUT[kf] = Mq[((KT) + 1) * 16 + kf * 4 + g16];                         \
    }                                                                          \
    f32x4 s_[4];                                                               \
    __builtin_amdgcn_s_setprio(1);                                             \
    _Pragma("unroll")                                                          \
    for (int kf = 0; kf < 4; ++kf) {                                           \
      int row = kf * 16 + l16;                                                 \
      short8 ak0 = *(const short8*)(Kc + row * 128 + ((g16 ^ l7) << 4));       \
      short8 ak1 = *(const short8*)(Kc + row * 128 + (((4 + g16) ^ l7) << 4)); \
      u64 bv = BIN[kf];                                                        \
      u32 blo = (u32)bv, bhi = (u32)(bv >> 32);                                \
      f32x4 acc;                                                               \
      acc[0] = __uint_as_float(blo << 16);                                     \
      acc[1] = __uint_as_float(blo & 0xffff0000u);                             \
      acc[2] = __uint_as_float(bhi << 16);                                     \
      acc[3] = __uint_as_float(bhi & 0xffff0000u);                             \
      acc = __builtin_amdgcn_mfma_f32_16x16x32_bf16(ak0, b_q[0], acc, 0, 0, 0);\
      acc = __builtin_amdgcn_mfma_f32_16x16x32_bf16(ak1, b_q[1], acc, 0, 0, 0);\
      s_[kf] = acc;                                                            \
    }                                                                          \
    __builtin_amdgcn_s_setprio(0);                                             \
    float sum = 0.f;                                                           \
    u32 c0a[4], c1a[4];                                                        \
    _Pragma("unroll")                                                          \
    for (int kf = 0; kf < 4; ++kf) {                                           \
      float e0 = __builtin_amdgcn_exp2f(s_[kf][0] - FIXED_MAX);                \
      float e1 = __builtin_amdgcn_exp2f(s_[kf][1] - FIXED_MAX);                \
      float e2 = __builtin_amdgcn_exp2f(s_[kf][2] - FIXED_MAX);                \
      float e3 = __builtin_amdgcn_exp2f(s_[kf][3] - FIXED_MAX);                \
      sum += (e0 + e1) + (e2 + e3);                                            \
      c0a[kf] = cvtpk(e0, e1);                                                 \
      c1a[kf] = cvtpk(e2, e3);                                                 \
    }                                                                          \
    lL += sum;                                                                 \
    u32x4 t0 = {c0a[0], c1a[0], c0a[1], c1a[1]};                               \
    u32x4 t1 = {c0a[2], c1a[2], c0a[3], c1a[3]};                               \
    short8 b_p0 = *(short8*)&t0;                                               \
    short8 b_p1 = *(short8*)&t1;                                               \
    __builtin_amdgcn_s_setprio(1);                                             \
    _Pragma("unroll")                                                          \
    for (int f = 0; f < 4; ++f) {                                              \
      int vrow = f * 16 + l16;                                                 \
      short8 av0 = *(const short8*)(Vc + vrow * 128 + ((g16 ^ l7) << 4));      \
      short8 av1 = *(const short8*)(Vc + vrow * 128 + (((4 + g16) ^ l7) << 4));\
      accO[f] = __builtin_amdgcn_mfma_f32_16x16x32_bf16(av0, b_p0, accO[f], 0, 0, 0); \
      accO[f] = __builtin_amdgcn_mfma_f32_16x16x32_bf16(av1, b_p1, accO[f], 0, 0, 0); \
    }                                                                          \
    __builtin_amdgcn_s_setprio(0);                                             \
  } while (0)

  for (int t = 0; t < 8; ++t) {
    ATTN_TILE(2 * t, 0, biasA, biasB);
    ATTN_TILE(2 * t + 1, 1, biasB, biasA);
  }
#undef ATTN_TILE

  // epilogue: reduce l across g16 groups once; O = Qh + accO^T / l
  float l = lL;
  l += __shfl_xor(l, 16, 64);
  l += __shfl_xor(l, 32, 64);
  float inv = 1.0f / fmaxf(l, 1e-20f);
#pragma unroll
  for (int f = 0; f < 4; ++f) {
    size_t o = (batch_row + q) * DMODEL + hb + f * 16 + g16 * 4;
    u64 qh = *(const u64*)(Qp + o);
    u64 ov = 0;
#pragma unroll
    for (int r = 0; r < 4; ++r) {
      float val = accO[f][r] * inv + bf2f((u16)(qh >> (r * 16)));
      ov |= ((u64)f2bf(val)) << (r * 16);
    }
    *(u64*)(O1 + o) = ov;
  }
}

// ---------------------------------------------------------------------------
// layernorm: one wave per 512-ch row. OUTF=0 -> bf16 out, OUTF=1 -> fp32 out
// ---------------------------------------------------------------------------
template<int OUTF>
__global__ __launch_bounds__(256) void ln_kernel(
    const u16* __restrict__ X, const float* __restrict__ g, const float* __restrict__ bb,
    void* __restrict__ outv)
{
  const int tid = threadIdx.x;
  const int wv = tid >> 6, lane = tid & 63;
  const size_t row = (size_t)blockIdx.x * 4 + wv;
  short8 x8 = *(const short8*)(X + row * 512 + lane * 8);
  float xf[8];
  float s = 0.f, s2 = 0.f;
#pragma unroll
  for (int i = 0; i < 8; ++i) {
    xf[i] = bf2f((u16)x8[i]);
    s += xf[i];
    s2 += xf[i] * xf[i];
  }
#pragma unroll
  for (int d = 1; d < 64; d <<= 1) {
    s += __shfl_xor(s, d, 64);
    s2 += __shfl_xor(s2, d, 64);
  }
  float mu = s * (1.f / 512.f);
  float var = s2 * (1.f / 512.f) - mu * mu;
  float rs = rsqrtf(var + 1e-5f);
  float4 ga = *(const float4*)(g + lane * 8);
  float4 gb = *(const float4*)(g + lane * 8 + 4);
  float4 ba = *(const float4*)(bb + lane * 8);
  float4 bc = *(const float4*)(bb + lane * 8 + 4);
  float gv[8] = {ga.x, ga.y, ga.z, ga.w, gb.x, gb.y, gb.z, gb.w};
  float bv[8] = {ba.x, ba.y, ba.z, ba.w, bc.x, bc.y, bc.z, bc.w};
  float y[8];
#pragma unroll
  for (int i = 0; i < 8; ++i) y[i] = (xf[i] - mu) * rs * gv[i] + bv[i];
  if (OUTF) {
    float* o = (float*)outv + row * 512 + lane * 8;
    float4 o1 = {y[0], y[1], y[2], y[3]};
    float4 o2 = {y[4], y[5], y[6], y[7]};
    *(float4*)o = o1;
    *(float4*)(o + 4) = o2;
  } else {
    short8 o;
#pragma unroll
    for (int i = 0; i < 8; ++i) o[i] = (short)f2bf(y[i]);
    *(short8*)((u16*)outv + row * 512 + lane * 8) = o;
  }
}

// ---------------------------------------------------------------------------
extern "C" void kernel_launch(void* const* d_in, const int* in_sizes, int n_in,
                              void* d_out, int out_size, void* d_ws, size_t ws_size,
                              hipStream_t stream) {
  (void)in_sizes; (void)n_in; (void)out_size; (void)ws_size;
  const float* Q  = (const float*)d_in[0];
  const float* K  = (const float*)d_in[1];
  const float* Wq = (const float*)d_in[2];
  const float* bq = (const float*)d_in[3];
  const float* Wk = (const float*)d_in[4];
  const float* bk = (const float*)d_in[5];
  const float* Wv = (const float*)d_in[6];
  const float* bv = (const float*)d_in[7];
  const float* Wo = (const float*)d_in[8];
  const float* bo = (const float*)d_in[9];
  const float* g0 = (const float*)d_in[10];
  const float* b0 = (const float*)d_in[11];
  const float* g1 = (const float*)d_in[12];
  const float* b1 = (const float*)d_in[13];
  const int*   M  = (const int*)d_in[14];
  float* out = (float*)d_out;
  char* ws = (char*)d_ws;

  u16* Qbf = (u16*)(ws + O_QBF);
  u16* Kbf = (u16*)(ws + O_KBF);
  u16* Wb  = (u16*)(ws + O_WB);
  u16* Qp  = (u16*)(ws + O_QP);
  u16* Kp  = (u16*)(ws + O_KP);
  u16* Vp  = (u16*)(ws + O_VP);
  u16* Mbias = (u16*)d_out;  // 16.77 MB, exactly out-size; dead until ln1
  u16* O1  = Kbf;   // Kbf dead after gemm1
  u16* Xn  = Qp;    // Qp dead after attn
  u16* Z   = Qbf;   // Qbf dead after gemm1

  prep_kernel<<<6400, 256, 0, stream>>>(Q, K, Wq, Wk, Wv, Wo, M, Qbf, Kbf, Wb, Mbias);
  gemm_bt<0><<<dim3(64, 4, 3), 256, 0, stream>>>(Qbf, Kbf, Wb, bq, bk, bv, Qp, nullptr);
  attn_kernel<<<1024, 256, 0, stream>>>(Qp, Kp, Vp, Mbias, O1);
  ln_kernel<0><<<2048, 256, 0, stream>>>(O1, g0, b0, (void*)Xn);
  gemm_bt<1><<<dim3(64, 4, 1), 256, 0, stream>>>(Xn, nullptr, Wb + 3 * 262144, bo,
                                                 nullptr, nullptr, Z, Xn);
  ln_kernel<1><<<2048, 256, 0, stream>>>(Z, g1, b1, (void*)out);
}

// Round 10
// 117.060 us; speedup vs baseline: 1.0114x; 1.0114x over previous
//
#include <hip/hip_runtime.h>

typedef unsigned short u16;
typedef unsigned int u32;
typedef unsigned long long u64;
typedef __attribute__((ext_vector_type(8))) short short8;
typedef __attribute__((ext_vector_type(4))) float f32x4;
typedef __attribute__((ext_vector_type(4))) u32 u32x4;

#define BATCH 8
#define NSEQ 1024
#define DMODEL 512
#define HDIM 64
// QK_SCALE * log2(e): softmax computed in exp2 domain
#define SCALE_LOG2E 0.06375871114929199f
#define FIXED_MAX 16.0f

// workspace byte offsets
#define O_QBF 0ULL
#define O_KBF 8388608ULL
#define O_WB  16777216ULL
#define O_QP  19922944ULL
#define O_KP  28311552ULL
#define O_VP  36700160ULL

__device__ __forceinline__ u16 f2bf(float f) {
  u32 u = __float_as_uint(f);
  u = (u + 0x7fffu + ((u >> 16) & 1u)) >> 16;
  return (u16)u;
}
__device__ __forceinline__ float bf2f(u16 s) {
  return __uint_as_float(((u32)s) << 16);
}
__device__ __forceinline__ void gload16(const void* g, void* l) {
  __builtin_amdgcn_global_load_lds((const __attribute__((address_space(1))) void*)g,
                                   (__attribute__((address_space(3))) void*)l, 16, 0, 0);
}
// pack two f32 -> u32 of 2 bf16 (lo = a, hi = b)
__device__ __forceinline__ u32 cvtpk(float a, float b) {
  u32 r;
  asm("v_cvt_pk_bf16_f32 %0, %1, %2" : "=v"(r) : "v"(a), "v"(b));
  return r;
}

// ---------------------------------------------------------------------------
// prep: fp32->bf16 Q/K, transpose-convert weights to [N][K],
//       M -> bf16 additive bias {0, -32768} stored in d_out (dead until ln1)
// ---------------------------------------------------------------------------
__global__ __launch_bounds__(256) void prep_kernel(
    const float* __restrict__ Q, const float* __restrict__ K,
    const float* __restrict__ Wq, const float* __restrict__ Wk,
    const float* __restrict__ Wv, const float* __restrict__ Wo,
    const int* __restrict__ M,
    u16* __restrict__ Qbf, u16* __restrict__ Kbf, u16* __restrict__ Wb,
    u16* __restrict__ Mbias)
{
  __shared__ float lds[64 * 68];
  const int bi = blockIdx.x, t = threadIdx.x;
  if (bi < 4096) {
    const float* src = (bi < 2048) ? Q : K;
    u16* dst = (bi < 2048) ? Qbf : Kbf;
    const int lb = bi & 2047;
    const size_t base = ((size_t)lb * 256 + t) * 8;
    float4 a = *(const float4*)(src + base);
    float4 c = *(const float4*)(src + base + 4);
    short8 o;
    o[0] = (short)f2bf(a.x); o[1] = (short)f2bf(a.y);
    o[2] = (short)f2bf(a.z); o[3] = (short)f2bf(a.w);
    o[4] = (short)f2bf(c.x); o[5] = (short)f2bf(c.y);
    o[6] = (short)f2bf(c.z); o[7] = (short)f2bf(c.w);
    *(short8*)(dst + base) = o;
  } else if (bi < 4352) {
    const int qid = bi - 4096;
    const int w = qid >> 6;
    const int tt = qid & 63;
    const int tr = tt >> 3, tc = tt & 7;          // 64x64 tile at (tr*64 k, tc*64 n)
    const float* W = (w == 0) ? Wq : (w == 1) ? Wk : (w == 2) ? Wv : Wo;
#pragma unroll
    for (int j = 0; j < 4; ++j) {
      int vi = j * 256 + t;
      int row = vi >> 4, c4 = vi & 15;
      float4 v = *(const float4*)(W + (size_t)(tr * 64 + row) * 512 + tc * 64 + c4 * 4);
      lds[row * 68 + c4 * 4 + 0] = v.x;
      lds[row * 68 + c4 * 4 + 1] = v.y;
      lds[row * 68 + c4 * 4 + 2] = v.z;
      lds[row * 68 + c4 * 4 + 3] = v.w;
    }
    __syncthreads();
    // 64 n-rows x 8 k8-chunks = 512 short8 stores -> exactly 2 iterations
#pragma unroll
    for (int j = 0; j < 2; ++j) {
      int oi = j * 256 + t;
      int nl = oi >> 3, k8 = oi & 7;
      short8 o;
#pragma unroll
      for (int i = 0; i < 8; ++i) o[i] = (short)f2bf(lds[(k8 * 8 + i) * 68 + nl]);
      *(short8*)(Wb + (size_t)w * 262144 + (size_t)(tc * 64 + nl) * 512 + tr * 64 + k8 * 8) = o;
    }
  } else {
    // mask -> bf16 additive bias: keep -> 0.0, masked -> -32768.0 (0xC700)
    const int pb = bi - 4352;                     // 2048 blocks
    const size_t idx = ((size_t)pb * 256 + t) * 16;
    const int4* Ms = (const int4*)(M + idx);
    int4 m0 = Ms[0], m1 = Ms[1], m2 = Ms[2], m3 = Ms[3];
    int mv[16] = {m0.x, m0.y, m0.z, m0.w, m1.x, m1.y, m1.z, m1.w,
                  m2.x, m2.y, m2.z, m2.w, m3.x, m3.y, m3.z, m3.w};
    short8 o0, o1;
#pragma unroll
    for (int i = 0; i < 8; ++i) {
      o0[i] = mv[i] ? (short)0 : (short)0xC700;
      o1[i] = mv[8 + i] ? (short)0 : (short)0xC700;
    }
    *(short8*)(Mbias + idx) = o0;
    *(short8*)(Mbias + idx + 8) = o1;
  }
}

// ---------------------------------------------------------------------------
// gemm_bt: C[M=8192,N=512] = A[M,512] * Wb^T (Wb stored [N][K]) + bias
// ---------------------------------------------------------------------------
template<int MODE>
__global__ __launch_bounds__(256) void gemm_bt(
    const u16* __restrict__ Aq, const u16* __restrict__ Ak,
    const u16* __restrict__ Wb,
    const float* __restrict__ b0, const float* __restrict__ b1, const float* __restrict__ b2,
    u16* __restrict__ outp, const u16* __restrict__ resid)
{
  __shared__ __align__(16) char Alds[8192];
  __shared__ __align__(16) char Blds[8192];
  const int tid = threadIdx.x;
  const int wv = tid >> 6, lane = tid & 63;
  const int g16 = lane >> 4, l16 = lane & 15;
  const int wr = wv >> 1, wc = wv & 1;
  const int bx = blockIdx.x, by = blockIdx.y, bz = blockIdx.z;

  const u16* A; const u16* W; const float* bias; u16* out;
  if (MODE == 0) {
    A = (bz == 0) ? Aq : Ak;
    W = Wb + (size_t)bz * 262144;
    bias = (bz == 0) ? b0 : ((bz == 1) ? b1 : b2);
    out = outp + (size_t)bz * 4194304;
  } else {
    A = Aq; W = Wb; bias = b0; out = outp;
  }

  const int m0 = bx * 128, n0 = by * 128;
  f32x4 acc[4][4] = {};

  for (int kt = 0; kt < 16; ++kt) {
    const int k0 = kt * 32;
#pragma unroll
    for (int r = 0; r < 2; ++r) {
      int idx = r * 256 + tid;
      int row = idx >> 2, sl = idx & 3;
      gload16(A + (size_t)(m0 + row) * 512 + k0 + sl * 8, Alds + r * 4096 + wv * 1024);
      gload16(W + (size_t)(n0 + row) * 512 + k0 + sl * 8, Blds + r * 4096 + wv * 1024);
    }
    __syncthreads();
    short8 af[4], bfr[4];
#pragma unroll
    for (int mt = 0; mt < 4; ++mt)
      af[mt] = *(const short8*)(Alds + (wr * 64 + mt * 16 + l16) * 64 + g16 * 16);
#pragma unroll
    for (int nt = 0; nt < 4; ++nt)
      bfr[nt] = *(const short8*)(Blds + (wc * 64 + nt * 16 + l16) * 64 + g16 * 16);
#pragma unroll
    for (int mt = 0; mt < 4; ++mt)
#pragma unroll
      for (int nt = 0; nt < 4; ++nt)
        acc[mt][nt] = __builtin_amdgcn_mfma_f32_16x16x32_bf16(af[mt], bfr[nt], acc[mt][nt], 0, 0, 0);
    __syncthreads();
  }

#pragma unroll
  for (int nt = 0; nt < 4; ++nt) {
    int col = n0 + wc * 64 + nt * 16 + l16;
    float bcol = bias[col];
#pragma unroll
    for (int mt = 0; mt < 4; ++mt) {
#pragma unroll
      for (int r = 0; r < 4; ++r) {
        int row = m0 + wr * 64 + mt * 16 + g16 * 4 + r;
        float v = acc[mt][nt][r] + bcol;
        if (MODE == 1) {
          v = fmaxf(v, 0.f) + bf2f(resid[(size_t)row * 512 + col]);
        }
        out[(size_t)row * 512 + col] = f2bf(v);
      }
    }
  }
}

// ---------------------------------------------------------------------------
// flash attention, swapped-operand, static-max softmax, lane-local PV,
// KBLK=128: TWO kv sub-tiles per barrier phase (8 phases instead of 16).
// Experiment: if the ~8200cy/tile wall is per-barrier-phase overhead, halving
// phase count halves attn time; if it scales with kv bytes, neutral.
// Counted waits: steady-state queue at phase top (oldest->newest) =
// K[4 gload_lds], V[16], bias[8] = 28 -> vmcnt(24) retires exactly K.
// Last phase: queue = K[4], bias[8] -> vmcnt(8). Never vmcnt(0) in loop.
// LDS 64 KB -> 2 blocks/CU (occupancy-insensitivity shown r4 vs r5).
// ---------------------------------------------------------------------------
__global__ __launch_bounds__(256, 2) void attn_kernel(
    const u16* __restrict__ Qp, const u16* __restrict__ Kp, const u16* __restrict__ Vp,
    const u16* __restrict__ Mbias, u16* __restrict__ O1)
{
  __shared__ __align__(16) char K_lds[2][16384];   // 2 sub-tiles [64 k][64 dk] each
  __shared__ __align__(16) char VT_lds[2][16384];  // 2 sub-tiles [64 dv][64 kappa]

  const int tid = threadIdx.x;
  const int wv = tid >> 6, lane = tid & 63;
  const int g16 = lane >> 4, l16 = lane & 15;
  const int l7 = l16 & 7;

  // bijective XCD swizzle: all 16 q-tiles of a (b,h) share one XCD's L2
  const int wg = blockIdx.x;                       // 1024 blocks
  const int swz = (wg & 7) * 128 + (wg >> 3);
  const int qt = swz & 15;
  const int h = (swz >> 4) & 7;
  const int b = swz >> 7;
  const int qg = qt * 64;
  const int hb = h * HDIM;
  const size_t batch_row = (size_t)b * NSEQ;

  const int q = qg + wv * 16 + l16;                // this lane's q column
  const int dv2 = (tid & 31) * 2;                  // V staging lanes
  const int kg = tid >> 5;                         // 0..7 = kc*4+gg
  const int v_kc = kg >> 2, v_gg = kg & 3;

  // hoist Q as B-operand frags, pre-scaled into the exp2 domain
  short8 b_q[2];
#pragma unroll
  for (int c = 0; c < 2; ++c) {
    short8 raw = *(const short8*)(Qp + (batch_row + q) * DMODEL + hb + c * 32 + g16 * 8);
    short8 sc;
#pragma unroll
    for (int j = 0; j < 8; ++j) sc[j] = (short)f2bf(bf2f((u16)raw[j]) * SCALE_LOG2E);
    b_q[c] = sc;
  }

  const u64* Mq = (const u64*)(Mbias + (batch_row + q) * 1024);

  auto stageK = [&](int kt2, char* dst) {
#pragma unroll
    for (int r = 0; r < 2; ++r) {
      int idx = r * 256 + tid;
      int row = idx >> 3, sl = idx & 7;
      int chunk = sl ^ (row & 7);
      gload16(Kp + (batch_row + kt2 * 64 + row) * DMODEL + hb + chunk * 8,
              dst + r * 4096 + wv * 1024);
    }
  };
  // load V rows in kappa order (lane-local PV labeling, verified r9)
  auto loadV = [&](int kt2, u32 (&vr)[8]) {
#pragma unroll
    for (int j = 0; j < 8; ++j) {
      int row = v_kc * 32 + (j >> 2) * 16 + v_gg * 4 + (j & 3);
      vr[j] = *(const u32*)(Vp + (batch_row + kt2 * 64 + row) * DMODEL + hb + dv2);
    }
  };
  auto writeVT = [&](const u32 (&vr)[8], char* dstv) {
    u32x4 lo, hi;
#pragma unroll
    for (int i = 0; i < 4; ++i) {
      lo[i] = __builtin_amdgcn_perm(vr[2 * i + 1], vr[2 * i], 0x05040100u);
      hi[i] = __builtin_amdgcn_perm(vr[2 * i + 1], vr[2 * i], 0x07060302u);
    }
    *(u32x4*)(dstv + dv2 * 128 + ((kg ^ (dv2 & 7)) << 4)) = lo;
    *(u32x4*)(dstv + (dv2 + 1) * 128 + ((kg ^ ((dv2 + 1) & 7)) << 4)) = hi;
  };

  float lL = 0.f;
  f32x4 accO[4] = {};

  u32 v0[8], v1[8];
  u64 biasA[8], biasB[8];

  // prologue: K tiles 0,1 -> K_lds[0]; V tiles 0,1 -> VT_lds[0]; V 2,3 -> regs
  stageK(0, &K_lds[0][0]);
  stageK(1, &K_lds[0][8192]);
  loadV(0, v0);
  loadV(1, v1);
#pragma unroll
  for (int kf = 0; kf < 4; ++kf) {
    biasA[kf] = Mq[kf * 4 + g16];
    biasA[4 + kf] = Mq[16 + kf * 4 + g16];
  }
  writeVT(v0, &VT_lds[0][0]);      // compiler-counted waits retire K0,K1,V0,V1
  writeVT(v1, &VT_lds[0][8192]);
  loadV(2, v0);
  loadV(3, v1);

// one kv sub-tile: QK(+bias C-in) -> exp2 -> lane-local P -> PV
#define SUBTILE(KCP, VCP, BARR, BOFF)                                          \
  do {                                                                         \
    f32x4 s_[4];                                                               \
    __builtin_amdgcn_s_setprio(1);                                             \
    _Pragma("unroll")                                                          \
    for (int kf = 0; kf < 4; ++kf) {                                           \
      int row = kf * 16 + l16;                                                 \
      short8 ak0 = *(const short8*)((KCP) + row * 128 + ((g16 ^ l7) << 4));    \
      short8 ak1 = *(const short8*)((KCP) + row * 128 + (((4 + g16) ^ l7) << 4)); \
      u64 bv = BARR[(BOFF) + kf];                                              \
      u32 blo = (u32)bv, bhi = (u32)(bv >> 32);                                \
      f32x4 acc;                                                               \
      acc[0] = __uint_as_float(blo << 16);                                     \
      acc[1] = __uint_as_float(blo & 0xffff0000u);                             \
      acc[2] = __uint_as_float(bhi << 16);                                     \
      acc[3] = __uint_as_float(bhi & 0xffff0000u);                             \
      acc = __builtin_amdgcn_mfma_f32_16x16x32_bf16(ak0, b_q[0], acc, 0, 0, 0);\
      acc = __builtin_amdgcn_mfma_f32_16x16x32_bf16(ak1, b_q[1], acc, 0, 0, 0);\
      s_[kf] = acc;                                                            \
    }                                                                          \
    __builtin_amdgcn_s_setprio(0);                                             \
    float sum = 0.f;                                                           \
    u32 c0a[4], c1a[4];                                                        \
    _Pragma("unroll")                                                          \
    for (int kf = 0; kf < 4; ++kf) {                                           \
      float e0 = __builtin_amdgcn_exp2f(s_[kf][0] - FIXED_MAX);                \
      float e1 = __builtin_amdgcn_exp2f(s_[kf][1] - FIXED_MAX);                \
      float e2 = __builtin_amdgcn_exp2f(s_[kf][2] - FIXED_MAX);                \
      float e3 = __builtin_amdgcn_exp2f(s_[kf][3] - FIXED_MAX);                \
      sum += (e0 + e1) + (e2 + e3);                                            \
      c0a[kf] = cvtpk(e0, e1);                                                 \
      c1a[kf] = cvtpk(e2, e3);                                                 \
    }                                                                          \
    lL += sum;                                                                 \
    u32x4 t0 = {c0a[0], c1a[0], c0a[1], c1a[1]};                               \
    u32x4 t1 = {c0a[2], c1a[2], c0a[3], c1a[3]};                               \
    short8 b_p0 = *(short8*)&t0;                                               \
    short8 b_p1 = *(short8*)&t1;                                               \
    __builtin_amdgcn_s_setprio(1);                                             \
    _Pragma("unroll")                                                          \
    for (int f = 0; f < 4; ++f) {                                              \
      int vrow = f * 16 + l16;                                                 \
      short8 av0 = *(const short8*)((VCP) + vrow * 128 + ((g16 ^ l7) << 4));   \
      short8 av1 = *(const short8*)((VCP) + vrow * 128 + (((4 + g16) ^ l7) << 4)); \
      accO[f] = __builtin_amdgcn_mfma_f32_16x16x32_bf16(av0, b_p0, accO[f], 0, 0, 0); \
      accO[f] = __builtin_amdgcn_mfma_f32_16x16x32_bf16(av1, b_p1, accO[f], 0, 0, 0); \
    }                                                                          \
    __builtin_amdgcn_s_setprio(0);                                             \
  } while (0)

// one barrier phase = two kv sub-tiles; prefetch next phase's K/V/bias.
// Issue order matters for the vmcnt derivation: stageK (4) -> loadV (16)
// -> loadBias (8); at next phase top vmcnt(24) retires exactly the K gloads.
#define ATTN_IT(IT, CUR, BIN, BOUT, VMCSTR)                                    \
  do {                                                                         \
    asm volatile("s_waitcnt vmcnt(" VMCSTR ") lgkmcnt(0)" ::: "memory");       \
    __builtin_amdgcn_sched_barrier(0);                                         \
    __builtin_amdgcn_s_barrier();                                              \
    __builtin_amdgcn_sched_barrier(0);                                         \
    char* Kc = &K_lds[CUR][0];                                                 \
    char* Vc = &VT_lds[CUR][0];                                                \
    if ((IT) < 7) {                                                            \
      writeVT(v0, &VT_lds[(CUR) ^ 1][0]);                                      \
      writeVT(v1, &VT_lds[(CUR) ^ 1][8192]);                                   \
      stageK(2 * (IT) + 2, &K_lds[(CUR) ^ 1][0]);                              \
      stageK(2 * (IT) + 3, &K_lds[(CUR) ^ 1][8192]);                           \
    }                                                                          \
    if ((IT) < 6) {                                                            \
      loadV(2 * (IT) + 4, v0);                                                 \
      loadV(2 * (IT) + 5, v1);                                                 \
    }                                                                          \
    if ((IT) < 7) {                                                            \
      _Pragma("unroll")                                                        \
      for (int kf = 0; kf < 4; ++kf) {                                         \
        BOUT[kf] = Mq[(2 * (IT) + 2) * 16 + kf * 4 + g16];                     \
        BOUT[4 + kf] = Mq[(2 * (IT) + 3) * 16 + kf * 4 + g16];                 \
      }                                                                        \
    }                                                                          \
    SUBTILE(Kc, Vc, BIN, 0);                                                   \
    SUBTILE(Kc + 8192, Vc + 8192, BIN, 4);                                     \
  } while (0)

  for (int t = 0; t < 3; ++t) {
    ATTN_IT(2 * t, 0, biasA, biasB, "24");
    ATTN_IT(2 * t + 1, 1, biasB, biasA, "24");
  }
  ATTN_IT(6, 0, biasA, biasB, "24");
  ATTN_IT(7, 1, biasB, biasA, "8");
#undef ATTN_IT
#undef SUBTILE

  // epilogue: reduce l across g16 groups once; O = Qh + accO^T / l
  float l = lL;
  l += __shfl_xor(l, 16, 64);
  l += __shfl_xor(l, 32, 64);
  float inv = 1.0f / fmaxf(l, 1e-20f);
#pragma unroll
  for (int f = 0; f < 4; ++f) {
    size_t o = (batch_row + q) * DMODEL + hb + f * 16 + g16 * 4;
    u64 qh = *(const u64*)(Qp + o);
    u64 ov = 0;
#pragma unroll
    for (int r = 0; r < 4; ++r) {
      float val = accO[f][r] * inv + bf2f((u16)(qh >> (r * 16)));
      ov |= ((u64)f2bf(val)) << (r * 16);
    }
    *(u64*)(O1 + o) = ov;
  }
}

// ---------------------------------------------------------------------------
// layernorm: one wave per 512-ch row. OUTF=0 -> bf16 out, OUTF=1 -> fp32 out
// ---------------------------------------------------------------------------
template<int OUTF>
__global__ __launch_bounds__(256) void ln_kernel(
    const u16* __restrict__ X, const float* __restrict__ g, const float* __restrict__ bb,
    void* __restrict__ outv)
{
  const int tid = threadIdx.x;
  const int wv = tid >> 6, lane = tid & 63;
  const size_t row = (size_t)blockIdx.x * 4 + wv;
  short8 x8 = *(const short8*)(X + row * 512 + lane * 8);
  float xf[8];
  float s = 0.f, s2 = 0.f;
#pragma unroll
  for (int i = 0; i < 8; ++i) {
    xf[i] = bf2f((u16)x8[i]);
    s += xf[i];
    s2 += xf[i] * xf[i];
  }
#pragma unroll
  for (int d = 1; d < 64; d <<= 1) {
    s += __shfl_xor(s, d, 64);
    s2 += __shfl_xor(s2, d, 64);
  }
  float mu = s * (1.f / 512.f);
  float var = s2 * (1.f / 512.f) - mu * mu;
  float rs = rsqrtf(var + 1e-5f);
  float4 ga = *(const float4*)(g + lane * 8);
  float4 gb = *(const float4*)(g + lane * 8 + 4);
  float4 ba = *(const float4*)(bb + lane * 8);
  float4 bc = *(const float4*)(bb + lane * 8 + 4);
  float gv[8] = {ga.x, ga.y, ga.z, ga.w, gb.x, gb.y, gb.z, gb.w};
  float bv[8] = {ba.x, ba.y, ba.z, ba.w, bc.x, bc.y, bc.z, bc.w};
  float y[8];
#pragma unroll
  for (int i = 0; i < 8; ++i) y[i] = (xf[i] - mu) * rs * gv[i] + bv[i];
  if (OUTF) {
    float* o = (float*)outv + row * 512 + lane * 8;
    float4 o1 = {y[0], y[1], y[2], y[3]};
    float4 o2 = {y[4], y[5], y[6], y[7]};
    *(float4*)o = o1;
    *(float4*)(o + 4) = o2;
  } else {
    short8 o;
#pragma unroll
    for (int i = 0; i < 8; ++i) o[i] = (short)f2bf(y[i]);
    *(short8*)((u16*)outv + row * 512 + lane * 8) = o;
  }
}

// ---------------------------------------------------------------------------
extern "C" void kernel_launch(void* const* d_in, const int* in_sizes, int n_in,
                              void* d_out, int out_size, void* d_ws, size_t ws_size,
                              hipStream_t stream) {
  (void)in_sizes; (void)n_in; (void)out_size; (void)ws_size;
  const float* Q  = (const float*)d_in[0];
  const float* K  = (const float*)d_in[1];
  const float* Wq = (const float*)d_in[2];
  const float* bq = (const float*)d_in[3];
  const float* Wk = (const float*)d_in[4];
  const float* bk = (const float*)d_in[5];
  const float* Wv = (const float*)d_in[6];
  const float* bv = (const float*)d_in[7];
  const float* Wo = (const float*)d_in[8];
  const float* bo = (const float*)d_in[9];
  const float* g0 = (const float*)d_in[10];
  const float* b0 = (const float*)d_in[11];
  const float* g1 = (const float*)d_in[12];
  const float* b1 = (const float*)d_in[13];
  const int*   M  = (const int*)d_in[14];
  float* out = (float*)d_out;
  char* ws = (char*)d_ws;

  u16* Qbf = (u16*)(ws + O_QBF);
  u16* Kbf = (u16*)(ws + O_KBF);
  u16* Wb  = (u16*)(ws + O_WB);
  u16* Qp  = (u16*)(ws + O_QP);
  u16* Kp  = (u16*)(ws + O_KP);
  u16* Vp  = (u16*)(ws + O_VP);
  u16* Mbias = (u16*)d_out;  // 16.77 MB, exactly out-size; dead until ln1
  u16* O1  = Kbf;   // Kbf dead after gemm1
  u16* Xn  = Qp;    // Qp dead after attn
  u16* Z   = Qbf;   // Qbf dead after gemm1

  prep_kernel<<<6400, 256, 0, stream>>>(Q, K, Wq, Wk, Wv, Wo, M, Qbf, Kbf, Wb, Mbias);
  gemm_bt<0><<<dim3(64, 4, 3), 256, 0, stream>>>(Qbf, Kbf, Wb, bq, bk, bv, Qp, nullptr);
  attn_kernel<<<1024, 256, 0, stream>>>(Qp, Kp, Vp, Mbias, O1);
  ln_kernel<0><<<2048, 256, 0, stream>>>(O1, g0, b0, (void*)Xn);
  gemm_bt<1><<<dim3(64, 4, 1), 256, 0, stream>>>(Xn, nullptr, Wb + 3 * 262144, bo,
                                                 nullptr, nullptr, Z, Xn);
  ln_kernel<1><<<2048, 256, 0, stream>>>(Z, g1, b1, (void*)out);
}

// Round 11
// 113.260 us; speedup vs baseline: 1.0453x; 1.0336x over previous
//
#include <hip/hip_runtime.h>

typedef unsigned short u16;
typedef unsigned int u32;
typedef unsigned long long u64;
typedef __attribute__((ext_vector_type(8))) short short8;
typedef __attribute__((ext_vector_type(4))) float f32x4;
typedef __attribute__((ext_vector_type(4))) u32 u32x4;

#define BATCH 8
#define NSEQ 1024
#define DMODEL 512
#define HDIM 64
// QK_SCALE * log2(e): softmax computed in exp2 domain
#define SCALE_LOG2E 0.06375871114929199f
#define FIXED_MAX 16.0f

// workspace byte offsets
#define O_QBF 0ULL
#define O_KBF 8388608ULL
#define O_WB  16777216ULL
#define O_MB  18874368ULL
#define O_QP  19922944ULL
#define O_KP  28311552ULL
#define O_VP  36700160ULL

__device__ __forceinline__ u16 f2bf(float f) {
  u32 u = __float_as_uint(f);
  u = (u + 0x7fffu + ((u >> 16) & 1u)) >> 16;
  return (u16)u;
}
__device__ __forceinline__ float bf2f(u16 s) {
  return __uint_as_float(((u32)s) << 16);
}
__device__ __forceinline__ void gload16(const void* g, void* l) {
  __builtin_amdgcn_global_load_lds((const __attribute__((address_space(1))) void*)g,
                                   (__attribute__((address_space(3))) void*)l, 16, 0, 0);
}
// pack two f32 -> u32 of 2 bf16 (lo = a, hi = b)
__device__ __forceinline__ u32 cvtpk(float a, float b) {
  u32 r;
  asm("v_cvt_pk_bf16_f32 %0, %1, %2" : "=v"(r) : "v"(a), "v"(b));
  return r;
}

// ---------------------------------------------------------------------------
// prep: fp32->bf16 Q/K, transpose-convert weights to [N][K],
//       pack M into u64 bitmask words (1 MB) via __ballot
// ---------------------------------------------------------------------------
__global__ __launch_bounds__(256) void prep_kernel(
    const float* __restrict__ Q, const float* __restrict__ K,
    const float* __restrict__ Wq, const float* __restrict__ Wk,
    const float* __restrict__ Wv, const float* __restrict__ Wo,
    const int* __restrict__ M,
    u16* __restrict__ Qbf, u16* __restrict__ Kbf, u16* __restrict__ Wb,
    u64* __restrict__ Mb)
{
  __shared__ float lds[64 * 68];
  const int bi = blockIdx.x, t = threadIdx.x;
  if (bi < 4096) {
    const float* src = (bi < 2048) ? Q : K;
    u16* dst = (bi < 2048) ? Qbf : Kbf;
    const int lb = bi & 2047;
    const size_t base = ((size_t)lb * 256 + t) * 8;
    float4 a = *(const float4*)(src + base);
    float4 c = *(const float4*)(src + base + 4);
    short8 o;
    o[0] = (short)f2bf(a.x); o[1] = (short)f2bf(a.y);
    o[2] = (short)f2bf(a.z); o[3] = (short)f2bf(a.w);
    o[4] = (short)f2bf(c.x); o[5] = (short)f2bf(c.y);
    o[6] = (short)f2bf(c.z); o[7] = (short)f2bf(c.w);
    *(short8*)(dst + base) = o;
  } else if (bi < 4352) {
    const int qid = bi - 4096;
    const int w = qid >> 6;
    const int tt = qid & 63;
    const int tr = tt >> 3, tc = tt & 7;          // 64x64 tile at (tr*64 k, tc*64 n)
    const float* W = (w == 0) ? Wq : (w == 1) ? Wk : (w == 2) ? Wv : Wo;
#pragma unroll
    for (int j = 0; j < 4; ++j) {
      int vi = j * 256 + t;
      int row = vi >> 4, c4 = vi & 15;
      float4 v = *(const float4*)(W + (size_t)(tr * 64 + row) * 512 + tc * 64 + c4 * 4);
      lds[row * 68 + c4 * 4 + 0] = v.x;
      lds[row * 68 + c4 * 4 + 1] = v.y;
      lds[row * 68 + c4 * 4 + 2] = v.z;
      lds[row * 68 + c4 * 4 + 3] = v.w;
    }
    __syncthreads();
    // 64 n-rows x 8 k8-chunks = 512 short8 stores -> exactly 2 iterations
#pragma unroll
    for (int j = 0; j < 2; ++j) {
      int oi = j * 256 + t;
      int nl = oi >> 3, k8 = oi & 7;
      short8 o;
#pragma unroll
      for (int i = 0; i < 8; ++i) o[i] = (short)f2bf(lds[(k8 * 8 + i) * 68 + nl]);
      *(short8*)(Wb + (size_t)w * 262144 + (size_t)(tc * 64 + nl) * 512 + tr * 64 + k8 * 8) = o;
    }
  } else {
    // pack M to bits: word (b,q,kc) bit k = M[b][q][kc*64+k] != 0  (r2-proven)
    const int pb = bi - 4352;                     // 1024 blocks
    const int wv = t >> 6, lane = t & 63;
    for (int i = 0; i < 32; ++i) {
      int widx = pb * 128 + wv * 32 + i;          // < 131072
      int kc = widx & 15;
      int qq = (widx >> 4) & 1023;
      int bb = widx >> 14;
      int mv = M[((size_t)bb * 1024 + qq) * 1024 + kc * 64 + lane];
      u64 bal = __ballot(mv != 0);
      if (lane == 0) Mb[widx] = bal;
    }
  }
}

// ---------------------------------------------------------------------------
// gemm_bt: C[M=8192,N=512] = A[M,512] * Wb^T (Wb stored [N][K]) + bias
// 1-D grid with XCD-locality swizzle: block p -> XCD p%8; all (by,bz) tiles
// of the 8 bx-panels owned by that XCD -> A panels stay L2-resident
// (per-XCD set: A 1-2 MB + W <=1.5 MB < 4 MB L2). MODE0: 768 blocks,
// MODE1: 256 blocks.
// ---------------------------------------------------------------------------
template<int MODE>
__global__ __launch_bounds__(256) void gemm_bt(
    const u16* __restrict__ Aq, const u16* __restrict__ Ak,
    const u16* __restrict__ Wb,
    const float* __restrict__ b0, const float* __restrict__ b1, const float* __restrict__ b2,
    u16* __restrict__ outp, const u16* __restrict__ resid)
{
  __shared__ __align__(16) char Alds[8192];
  __shared__ __align__(16) char Blds[8192];
  const int tid = threadIdx.x;
  const int wv = tid >> 6, lane = tid & 63;
  const int g16 = lane >> 4, l16 = lane & 15;
  const int wr = wv >> 1, wc = wv & 1;

  const int p = blockIdx.x;
  const int xcd = p & 7, rest = p >> 3;
  const int bx = xcd + ((rest & 7) << 3);        // 0..63
  const int q2 = rest >> 3;                      // MODE0: 0..11, MODE1: 0..3
  const int by = (MODE == 0) ? (q2 & 3) : q2;
  const int bz = (MODE == 0) ? (q2 >> 2) : 0;

  const u16* A; const u16* W; const float* bias; u16* out;
  if (MODE == 0) {
    A = (bz == 0) ? Aq : Ak;
    W = Wb + (size_t)bz * 262144;
    bias = (bz == 0) ? b0 : ((bz == 1) ? b1 : b2);
    out = outp + (size_t)bz * 4194304;
  } else {
    A = Aq; W = Wb; bias = b0; out = outp;
  }

  const int m0 = bx * 128, n0 = by * 128;
  f32x4 acc[4][4] = {};

  for (int kt = 0; kt < 16; ++kt) {
    const int k0 = kt * 32;
#pragma unroll
    for (int r = 0; r < 2; ++r) {
      int idx = r * 256 + tid;
      int row = idx >> 2, sl = idx & 3;
      gload16(A + (size_t)(m0 + row) * 512 + k0 + sl * 8, Alds + r * 4096 + wv * 1024);
      gload16(W + (size_t)(n0 + row) * 512 + k0 + sl * 8, Blds + r * 4096 + wv * 1024);
    }
    __syncthreads();
    short8 af[4], bfr[4];
#pragma unroll
    for (int mt = 0; mt < 4; ++mt)
      af[mt] = *(const short8*)(Alds + (wr * 64 + mt * 16 + l16) * 64 + g16 * 16);
#pragma unroll
    for (int nt = 0; nt < 4; ++nt)
      bfr[nt] = *(const short8*)(Blds + (wc * 64 + nt * 16 + l16) * 64 + g16 * 16);
#pragma unroll
    for (int mt = 0; mt < 4; ++mt)
#pragma unroll
      for (int nt = 0; nt < 4; ++nt)
        acc[mt][nt] = __builtin_amdgcn_mfma_f32_16x16x32_bf16(af[mt], bfr[nt], acc[mt][nt], 0, 0, 0);
    __syncthreads();
  }

#pragma unroll
  for (int nt = 0; nt < 4; ++nt) {
    int col = n0 + wc * 64 + nt * 16 + l16;
    float bcol = bias[col];
#pragma unroll
    for (int mt = 0; mt < 4; ++mt) {
#pragma unroll
      for (int r = 0; r < 4; ++r) {
        int row = m0 + wr * 64 + mt * 16 + g16 * 4 + r;
        float v = acc[mt][nt][r] + bcol;
        if (MODE == 1) {
          v = fmaxf(v, 0.f) + bf2f(resid[(size_t)row * 512 + col]);
        }
        out[(size_t)row * 512 + col] = f2bf(v);
      }
    }
  }
}

// ---------------------------------------------------------------------------
// flash attention (r9 structure, best=54.5us): swapped-operand, static-max
// softmax, lane-local PV (kappa labeling), K via global_load_lds dbuf, V^T
// reg-staged dbuf. Mask now a packed u64 word per (q, kv-tile), unpacked
// in-register to the bias C-in fragment (bit k = kf*16+g16*4+r, r3-verified).
// Per tile: s_waitcnt vmcnt(8) lgkmcnt(0) + raw s_barrier (never vmcnt(0)).
// Queue at tile top (oldest->newest): K[2 gload_lds], V[8], mks[1] = 11;
// vmcnt(8) retires exactly K (one-slot safety vs issue-order drift).
// ---------------------------------------------------------------------------
__global__ __launch_bounds__(256, 4) void attn_kernel(
    const u16* __restrict__ Qp, const u16* __restrict__ Kp, const u16* __restrict__ Vp,
    const u64* __restrict__ Mb, u16* __restrict__ O1)
{
  __shared__ __align__(16) char K_lds[2][8192];    // [64 k][64 dk] bf16, chunk-swizzled
  __shared__ __align__(16) char VT_lds[2][8192];   // [64 dv][64 kappa] bf16, chunk-swizzled

  const int tid = threadIdx.x;
  const int wv = tid >> 6, lane = tid & 63;
  const int g16 = lane >> 4, l16 = lane & 15;
  const int l7 = l16 & 7;

  // bijective XCD swizzle: all 16 q-tiles of a (b,h) share one XCD's L2
  const int wg = blockIdx.x;                       // 1024 blocks
  const int swz = (wg & 7) * 128 + (wg >> 3);
  const int qt = swz & 15;
  const int h = (swz >> 4) & 7;
  const int b = swz >> 7;
  const int qg = qt * 64;
  const int hb = h * HDIM;
  const size_t batch_row = (size_t)b * NSEQ;

  const int q = qg + wv * 16 + l16;                // this lane's q column
  const int dv2 = (tid & 31) * 2;                  // V staging lanes
  const int kg = tid >> 5;                         // 0..7 = kc*4+gg
  const int v_kc = kg >> 2, v_gg = kg & 3;

  // hoist Q as B-operand frags, pre-scaled into the exp2 domain
  short8 b_q[2];
#pragma unroll
  for (int c = 0; c < 2; ++c) {
    short8 raw = *(const short8*)(Qp + (batch_row + q) * DMODEL + hb + c * 32 + g16 * 8);
    short8 sc;
#pragma unroll
    for (int j = 0; j < 8; ++j) sc[j] = (short)f2bf(bf2f((u16)raw[j]) * SCALE_LOG2E);
    b_q[c] = sc;
  }

  const u64* Mq = Mb + (batch_row + q) * 16;

  auto stageK = [&](int kt2, char* dst) {
#pragma unroll
    for (int r = 0; r < 2; ++r) {
      int idx = r * 256 + tid;
      int row = idx >> 3, sl = idx & 7;
      int chunk = sl ^ (row & 7);
      gload16(Kp + (batch_row + kt2 * 64 + row) * DMODEL + hb + chunk * 8,
              dst + r * 4096 + wv * 1024);
    }
  };
  // load V rows in kappa order (lane-local PV labeling, verified r9)
  auto loadV = [&](int kt2, u32 (&vr)[8]) {
#pragma unroll
    for (int j = 0; j < 8; ++j) {
      int row = v_kc * 32 + (j >> 2) * 16 + v_gg * 4 + (j & 3);
      vr[j] = *(const u32*)(Vp + (batch_row + kt2 * 64 + row) * DMODEL + hb + dv2);
    }
  };
  auto writeVT = [&](const u32 (&vr)[8], char* dstv) {
    u32x4 lo, hi;
#pragma unroll
    for (int i = 0; i < 4; ++i) {
      lo[i] = __builtin_amdgcn_perm(vr[2 * i + 1], vr[2 * i], 0x05040100u);
      hi[i] = __builtin_amdgcn_perm(vr[2 * i + 1], vr[2 * i], 0x07060302u);
    }
    *(u32x4*)(dstv + dv2 * 128 + ((kg ^ (dv2 & 7)) << 4)) = lo;
    *(u32x4*)(dstv + (dv2 + 1) * 128 + ((kg ^ ((dv2 + 1) & 7)) << 4)) = hi;
  };

  float lL = 0.f;
  f32x4 accO[4] = {};

  u32 vreg[8];
  u64 mksA, mksB;

  // prologue: stage tile 0; entering tile 0 the queue is mks0[<=1], V1[8]
  stageK(0, &K_lds[0][0]);
  loadV(0, vreg);
  mksA = Mq[0];
  writeVT(vreg, &VT_lds[0][0]);   // compiler-counted wait retires K0+V0 here
  loadV(1, vreg);

#define ATTN_TILE(KT, CUR, MKS, MKSN)                                          \
  do {                                                                         \
    asm volatile("s_waitcnt vmcnt(8) lgkmcnt(0)" ::: "memory");                \
    __builtin_amdgcn_sched_barrier(0);                                         \
    __builtin_amdgcn_s_barrier();                                              \
    __builtin_amdgcn_sched_barrier(0);                                         \
    char* Kc = &K_lds[CUR][0];                                                 \
    char* Vc = &VT_lds[CUR][0];                                                \
    if ((KT) < 15) {                                                           \
      writeVT(vreg, &VT_lds[(CUR) ^ 1][0]);                                    \
      stageK((KT) + 1, &K_lds[(CUR) ^ 1][0]);                                  \
      loadV((KT) + 2 < 16 ? (KT) + 2 : 15, vreg);                              \
      MKSN = Mq[(KT) + 1];                                                     \
    }                                                                          \
    f32x4 s_[4];                                                               \
    __builtin_amdgcn_s_setprio(1);                                             \
    _Pragma("unroll")                                                          \
    for (int kf = 0; kf < 4; ++kf) {                                           \
      int row = kf * 16 + l16;                                                 \
      short8 ak0 = *(const short8*)(Kc + row * 128 + ((g16 ^ l7) << 4));       \
      short8 ak1 = *(const short8*)(Kc + row * 128 + (((4 + g16) ^ l7) << 4)); \
      u32 nib = ((u32)((MKS) >> (kf * 16 + g16 * 4))) & 15u;                   \
      f32x4 acc;                                                               \
      acc[0] = (nib & 1u) ? 0.f : -32768.f;                                    \
      acc[1] = (nib & 2u) ? 0.f : -32768.f;                                    \
      acc[2] = (nib & 4u) ? 0.f : -32768.f;                                    \
      acc[3] = (nib & 8u) ? 0.f : -32768.f;                                    \
      acc = __builtin_amdgcn_mfma_f32_16x16x32_bf16(ak0, b_q[0], acc, 0, 0, 0);\
      acc = __builtin_amdgcn_mfma_f32_16x16x32_bf16(ak1, b_q[1], acc, 0, 0, 0);\
      s_[kf] = acc;                                                            \
    }                                                                          \
    __builtin_amdgcn_s_setprio(0);                                             \
    float sum = 0.f;                                                           \
    u32 c0a[4], c1a[4];                                                        \
    _Pragma("unroll")                                                          \
    for (int kf = 0; kf < 4; ++kf) {                                           \
      float e0 = __builtin_amdgcn_exp2f(s_[kf][0] - FIXED_MAX);                \
      float e1 = __builtin_amdgcn_exp2f(s_[kf][1] - FIXED_MAX);                \
      float e2 = __builtin_amdgcn_exp2f(s_[kf][2] - FIXED_MAX);                \
      float e3 = __builtin_amdgcn_exp2f(s_[kf][3] - FIXED_MAX);                \
      sum += (e0 + e1) + (e2 + e3);                                            \
      c0a[kf] = cvtpk(e0, e1);                                                 \
      c1a[kf] = cvtpk(e2, e3);                                                 \
    }                                                                          \
    lL += sum;                                                                 \
    u32x4 t0 = {c0a[0], c1a[0], c0a[1], c1a[1]};                               \
    u32x4 t1 = {c0a[2], c1a[2], c0a[3], c1a[3]};                               \
    short8 b_p0 = *(short8*)&t0;                                               \
    short8 b_p1 = *(short8*)&t1;                                               \
    __builtin_amdgcn_s_setprio(1);                                             \
    _Pragma("unroll")                                                          \
    for (int f = 0; f < 4; ++f) {                                              \
      int vrow = f * 16 + l16;                                                 \
      short8 av0 = *(const short8*)(Vc + vrow * 128 + ((g16 ^ l7) << 4));      \
      short8 av1 = *(const short8*)(Vc + vrow * 128 + (((4 + g16) ^ l7) << 4));\
      accO[f] = __builtin_amdgcn_mfma_f32_16x16x32_bf16(av0, b_p0, accO[f], 0, 0, 0); \
      accO[f] = __builtin_amdgcn_mfma_f32_16x16x32_bf16(av1, b_p1, accO[f], 0, 0, 0); \
    }                                                                          \
    __builtin_amdgcn_s_setprio(0);                                             \
  } while (0)

  for (int t = 0; t < 8; ++t) {
    ATTN_TILE(2 * t, 0, mksA, mksB);
    ATTN_TILE(2 * t + 1, 1, mksB, mksA);
  }
#undef ATTN_TILE

  // epilogue: reduce l across g16 groups once; O = Qh + accO^T / l
  float l = lL;
  l += __shfl_xor(l, 16, 64);
  l += __shfl_xor(l, 32, 64);
  float inv = 1.0f / fmaxf(l, 1e-20f);
#pragma unroll
  for (int f = 0; f < 4; ++f) {
    size_t o = (batch_row + q) * DMODEL + hb + f * 16 + g16 * 4;
    u64 qh = *(const u64*)(Qp + o);
    u64 ov = 0;
#pragma unroll
    for (int r = 0; r < 4; ++r) {
      float val = accO[f][r] * inv + bf2f((u16)(qh >> (r * 16)));
      ov |= ((u64)f2bf(val)) << (r * 16);
    }
    *(u64*)(O1 + o) = ov;
  }
}

// ---------------------------------------------------------------------------
// layernorm: one wave per 512-ch row. OUTF=0 -> bf16 out, OUTF=1 -> fp32 out
// ---------------------------------------------------------------------------
template<int OUTF>
__global__ __launch_bounds__(256) void ln_kernel(
    const u16* __restrict__ X, const float* __restrict__ g, const float* __restrict__ bb,
    void* __restrict__ outv)
{
  const int tid = threadIdx.x;
  const int wv = tid >> 6, lane = tid & 63;
  const size_t row = (size_t)blockIdx.x * 4 + wv;
  short8 x8 = *(const short8*)(X + row * 512 + lane * 8);
  float xf[8];
  float s = 0.f, s2 = 0.f;
#pragma unroll
  for (int i = 0; i < 8; ++i) {
    xf[i] = bf2f((u16)x8[i]);
    s += xf[i];
    s2 += xf[i] * xf[i];
  }
#pragma unroll
  for (int d = 1; d < 64; d <<= 1) {
    s += __shfl_xor(s, d, 64);
    s2 += __shfl_xor(s2, d, 64);
  }
  float mu = s * (1.f / 512.f);
  float var = s2 * (1.f / 512.f) - mu * mu;
  float rs = rsqrtf(var + 1e-5f);
  float4 ga = *(const float4*)(g + lane * 8);
  float4 gb = *(const float4*)(g + lane * 8 + 4);
  float4 ba = *(const float4*)(bb + lane * 8);
  float4 bc = *(const float4*)(bb + lane * 8 + 4);
  float gv[8] = {ga.x, ga.y, ga.z, ga.w, gb.x, gb.y, gb.z, gb.w};
  float bv[8] = {ba.x, ba.y, ba.z, ba.w, bc.x, bc.y, bc.z, bc.w};
  float y[8];
#pragma unroll
  for (int i = 0; i < 8; ++i) y[i] = (xf[i] - mu) * rs * gv[i] + bv[i];
  if (OUTF) {
    float* o = (float*)outv + row * 512 + lane * 8;
    float4 o1 = {y[0], y[1], y[2], y[3]};
    float4 o2 = {y[4], y[5], y[6], y[7]};
    *(float4*)o = o1;
    *(float4*)(o + 4) = o2;
  } else {
    short8 o;
#pragma unroll
    for (int i = 0; i < 8; ++i) o[i] = (short)f2bf(y[i]);
    *(short8*)((u16*)outv + row * 512 + lane * 8) = o;
  }
}

// ---------------------------------------------------------------------------
extern "C" void kernel_launch(void* const* d_in, const int* in_sizes, int n_in,
                              void* d_out, int out_size, void* d_ws, size_t ws_size,
                              hipStream_t stream) {
  (void)in_sizes; (void)n_in; (void)out_size; (void)ws_size;
  const float* Q  = (const float*)d_in[0];
  const float* K  = (const float*)d_in[1];
  const float* Wq = (const float*)d_in[2];
  const float* bq = (const float*)d_in[3];
  const float* Wk = (const float*)d_in[4];
  const float* bk = (const float*)d_in[5];
  const float* Wv = (const float*)d_in[6];
  const float* bv = (const float*)d_in[7];
  const float* Wo = (const float*)d_in[8];
  const float* bo = (const float*)d_in[9];
  const float* g0 = (const float*)d_in[10];
  const float* b0 = (const float*)d_in[11];
  const float* g1 = (const float*)d_in[12];
  const float* b1 = (const float*)d_in[13];
  const int*   M  = (const int*)d_in[14];
  float* out = (float*)d_out;
  char* ws = (char*)d_ws;

  u16* Qbf = (u16*)(ws + O_QBF);
  u16* Kbf = (u16*)(ws + O_KBF);
  u16* Wb  = (u16*)(ws + O_WB);
  u64* Mb  = (u64*)(ws + O_MB);
  u16* Qp  = (u16*)(ws + O_QP);
  u16* Kp  = (u16*)(ws + O_KP);
  u16* Vp  = (u16*)(ws + O_VP);
  u16* O1  = Kbf;   // Kbf dead after gemm1
  u16* Xn  = Qp;    // Qp dead after attn
  u16* Z   = Qbf;   // Qbf dead after gemm1

  prep_kernel<<<5376, 256, 0, stream>>>(Q, K, Wq, Wk, Wv, Wo, M, Qbf, Kbf, Wb, Mb);
  gemm_bt<0><<<768, 256, 0, stream>>>(Qbf, Kbf, Wb, bq, bk, bv, Qp, nullptr);
  attn_kernel<<<1024, 256, 0, stream>>>(Qp, Kp, Vp, Mb, O1);
  ln_kernel<0><<<2048, 256, 0, stream>>>(O1, g0, b0, (void*)Xn);
  gemm_bt<1><<<256, 256, 0, stream>>>(Xn, nullptr, Wb + 3 * 262144, bo,
                                      nullptr, nullptr, Z, Xn);
  ln_kernel<1><<<2048, 256, 0, stream>>>(Z, g1, b1, (void*)out);
}